// Round 6
// baseline (168.179 us; speedup 1.0000x reference)
//
#include <hip/hip_runtime.h>
#include <hip/hip_bf16.h>

// Shapes (fixed by the reference)
#define BB 32          // batch
#define CC 1024        // channels
#define HWSZ 576       // H*W
#define KCTX 8         // CONTEXT_LEN
#define TT 9           // K+1
#define NH 8
#define HD 128

#define GBM 32
#define GBN 128
#define GBK 32

#define NS_KV 4        // split-K for KV gemm (SKLEN 256)
#define NS_Q  8        // split-K for Q gemm  (SKLEN 128)

#define KV_MN (288 * 2048)
#define Q_MN  (32 * 1024)

typedef float v4f __attribute__((ext_vector_type(4)));

// ---------------------------------------------------------------------------
// K1: spatial mean pooling -> context [B][T][C].
// 16 lanes per row, 4 rows per wave. Buffer rows (memory order, NT loads)
// first; h_current rows last with cached loads (stay L3-resident for K4).
// ---------------------------------------------------------------------------
__global__ __launch_bounds__(256) void pool_kernel(
    const float* __restrict__ hbuf,   // [K][B][C][H][W]
    const float* __restrict__ hcur,   // [B][C][H][W]
    float* __restrict__ ctx)          // [B][T][C]
{
    const int wave = threadIdx.x >> 6;
    const int lane = threadIdx.x & 63;
    const int sub  = lane >> 4;        // row-within-wave 0..3
    const int l16  = lane & 15;
    const int stride = gridDim.x * 16; // rows per full sweep
    const int nrows = BB * TT * CC;    // 294912

    for (int r0 = (blockIdx.x * 4 + wave) * 4; r0 < nrows; r0 += stride) {
        const int r = r0 + sub;
        v4f acc = {0.f, 0.f, 0.f, 0.f};
        int cidx;
        if (r < KCTX * BB * CC) {                 // buffer rows, memory order
            const v4f* s4 = (const v4f*)(hbuf + (size_t)r * HWSZ);
            const int t = r >> 15;
            const int b = (r >> 10) & 31;
            cidx = (b * TT + t) * CC + (r & (CC - 1));
#pragma unroll
            for (int j = 0; j < 9; ++j)
                acc += __builtin_nontemporal_load(s4 + l16 + 16 * j);
        } else {                                  // current rows, last, cached
            const int rc = r - KCTX * BB * CC;
            const v4f* s4 = (const v4f*)(hcur + (size_t)rc * HWSZ);
            cidx = ((rc >> 10) * TT + KCTX) * CC + (rc & (CC - 1));
#pragma unroll
            for (int j = 0; j < 9; ++j)
                acc += s4[l16 + 16 * j];
        }
        float sum = acc.x + acc.y + acc.z + acc.w;
        sum += __shfl_xor(sum, 1);
        sum += __shfl_xor(sum, 2);
        sum += __shfl_xor(sum, 4);
        sum += __shfl_xor(sum, 8);
        if (l16 == 0) ctx[cidx] = sum * (1.0f / 576.0f);
    }
}

// ---------------------------------------------------------------------------
// Shared GEMM tile body (32x128 tile, one K slice).
// ---------------------------------------------------------------------------
__device__ __forceinline__ void gemm_tile_body(
    const float* __restrict__ Ablk, int lda,
    const float* __restrict__ Bblk, int ldb,
    float* __restrict__ Yout, int ldy,
    int k0, int klen,
    float (*As)[GBK + 4], float (*Bs)[GBN + 4])
{
    const int tid = threadIdx.x;
    const int tx = tid & 15;
    const int ty = tid >> 4;

    float acc0[8], acc1[8];
#pragma unroll
    for (int i = 0; i < 8; ++i) { acc0[i] = 0.f; acc1[i] = 0.f; }

    for (int kt = k0; kt < k0 + klen; kt += GBK) {
        {
            const int row = tid >> 3;
            const int kc = (tid & 7) << 2;
            float4 a = *(const float4*)(Ablk + (size_t)row * lda + kt + kc);
            *(float4*)(&As[row][kc]) = a;
        }
        {
            const int kc = (tid & 7) << 2;
            const int r0 = tid >> 3;
#pragma unroll
            for (int rr = 0; rr < 4; ++rr) {
                const int row = r0 + rr * 32;
                float4 bv = *(const float4*)(Bblk + (size_t)row * ldb + kt + kc);
                Bs[kc + 0][row] = bv.x;
                Bs[kc + 1][row] = bv.y;
                Bs[kc + 2][row] = bv.z;
                Bs[kc + 3][row] = bv.w;
            }
        }
        __syncthreads();

#pragma unroll
        for (int k4 = 0; k4 < GBK; k4 += 4) {
            float4 a0 = *(const float4*)(&As[ty * 2 + 0][k4]);
            float4 a1 = *(const float4*)(&As[ty * 2 + 1][k4]);
            const float a0v[4] = {a0.x, a0.y, a0.z, a0.w};
            const float a1v[4] = {a1.x, a1.y, a1.z, a1.w};
#pragma unroll
            for (int i = 0; i < 4; ++i) {
                float4 blo = *(const float4*)(&Bs[k4 + i][tx * 8]);
                float4 bhi = *(const float4*)(&Bs[k4 + i][tx * 8 + 4]);
                acc0[0] += a0v[i] * blo.x;  acc0[1] += a0v[i] * blo.y;
                acc0[2] += a0v[i] * blo.z;  acc0[3] += a0v[i] * blo.w;
                acc0[4] += a0v[i] * bhi.x;  acc0[5] += a0v[i] * bhi.y;
                acc0[6] += a0v[i] * bhi.z;  acc0[7] += a0v[i] * bhi.w;
                acc1[0] += a1v[i] * blo.x;  acc1[1] += a1v[i] * blo.y;
                acc1[2] += a1v[i] * blo.z;  acc1[3] += a1v[i] * blo.w;
                acc1[4] += a1v[i] * bhi.x;  acc1[5] += a1v[i] * bhi.y;
                acc1[6] += a1v[i] * bhi.z;  acc1[7] += a1v[i] * bhi.w;
            }
        }
        __syncthreads();
    }

    const int col = tx * 8;
    const int row0 = ty * 2;
    float* y0 = Yout + (size_t)row0 * ldy + col;
    float* y1 = y0 + ldy;
    *(float4*)(y0 + 0) = make_float4(acc0[0], acc0[1], acc0[2], acc0[3]);
    *(float4*)(y0 + 4) = make_float4(acc0[4], acc0[5], acc0[6], acc0[7]);
    *(float4*)(y1 + 0) = make_float4(acc1[0], acc1[1], acc1[2], acc1[3]);
    *(float4*)(y1 + 4) = make_float4(acc1[4], acc1[5], acc1[6], acc1[7]);
}

// ---------------------------------------------------------------------------
// K2: Q (64 blocks) + KV (576 blocks) projections in ONE launch.
// ---------------------------------------------------------------------------
__global__ __launch_bounds__(256) void qkv_gemm(
    const float* __restrict__ ctx, const float* __restrict__ Wqkv,
    float* __restrict__ qpart, float* __restrict__ kvpart)
{
    __shared__ float As[GBM][GBK + 4];
    __shared__ float Bs[GBK][GBN + 4];

    const int bid = blockIdx.x;
    if (bid < NS_Q * 8) {
        const int s = bid & (NS_Q - 1);
        const int bn = bid >> 3;
        gemm_tile_body(ctx + 8 * CC, TT * CC,
                       Wqkv + (size_t)bn * GBN * CC, CC,
                       qpart + (size_t)s * Q_MN + bn * GBN, 1024,
                       s * (1024 / NS_Q), 1024 / NS_Q, As, Bs);
    } else {
        const int rel = bid - NS_Q * 8;
        const int s = rel & (NS_KV - 1);
        const int tile = rel >> 2;            // 0..143
        const int bm = tile >> 4;             // 0..8
        const int bn = tile & 15;             // 0..15
        gemm_tile_body(ctx + (size_t)bm * GBM * CC, CC,
                       Wqkv + (size_t)CC * CC + (size_t)bn * GBN * CC, CC,
                       kvpart + (size_t)s * KV_MN + (size_t)bm * GBM * 2048 + bn * GBN, 2048,
                       s * (1024 / NS_KV), 1024 / NS_KV, As, Bs);
    }
}

// ---------------------------------------------------------------------------
// K3: attention, last query only. One wave per block, 256 blocks.
// Sums split-K partials of q and kv inline (L2/L3-hot).
// ---------------------------------------------------------------------------
__global__ __launch_bounds__(64) void attn_kernel(
    const float* __restrict__ kvpart,   // NS_KV slabs of [288][2048]
    const float* __restrict__ qpart,    // NS_Q slabs of [32][1024]
    const float* __restrict__ rel_emb,  // [17][8]
    float* __restrict__ attn_out)       // [B][C]
{
    const int lane = threadIdx.x;
    const int pair = blockIdx.x;              // 0..255
    const int b = pair >> 3;
    const int h = pair & 7;
    const float scale = 0.08838834764831845f; // 1/sqrt(128)

    const int qoff = b * CC + h * HD;
    float q1 = 0.f, q2 = 0.f;
#pragma unroll
    for (int s = 0; s < NS_Q; ++s) {
        q1 += qpart[(size_t)s * Q_MN + qoff + lane];
        q2 += qpart[(size_t)s * Q_MN + qoff + lane + 64];
    }
    q1 *= scale; q2 *= scale;

    float sc[TT];
#pragma unroll
    for (int j = 0; j < TT; ++j) {
        const size_t base = (size_t)(b * TT + j) * 2048 + h * HD;
        float k1 = 0.f, k2 = 0.f;
#pragma unroll
        for (int s = 0; s < NS_KV; ++s) {
            k1 += kvpart[(size_t)s * KV_MN + base + lane];
            k2 += kvpart[(size_t)s * KV_MN + base + lane + 64];
        }
        float p = q1 * k1 + q2 * k2;
#pragma unroll
        for (int off = 32; off; off >>= 1) p += __shfl_xor(p, off);
        sc[j] = p + rel_emb[(2 * KCTX - j) * NH + h];
    }
    float m = sc[0];
#pragma unroll
    for (int j = 1; j < TT; ++j) m = fmaxf(m, sc[j]);
    float sum = 0.f;
#pragma unroll
    for (int j = 0; j < TT; ++j) { sc[j] = expf(sc[j] - m); sum += sc[j]; }
    const float inv = 1.0f / sum;

    float a1 = 0.f, a2 = 0.f;
#pragma unroll
    for (int j = 0; j < TT; ++j) {
        const size_t base = (size_t)(b * TT + j) * 2048 + 1024 + h * HD;
        float v1 = 0.f, v2 = 0.f;
#pragma unroll
        for (int s = 0; s < NS_KV; ++s) {
            v1 += kvpart[(size_t)s * KV_MN + base + lane];
            v2 += kvpart[(size_t)s * KV_MN + base + lane + 64];
        }
        a1 += sc[j] * v1;
        a2 += sc[j] * v2;
    }
    attn_out[qoff + lane] = a1 * inv;
    attn_out[qoff + lane + 64] = a2 * inv;
}

// ---------------------------------------------------------------------------
// K4: fused out-projection + broadcast residual add, 2 rows per wave-iter.
// Dot loads for both rows issue together (2x MLP), shfl chains overlap,
// then both rows stream (L3-hot h_current read, NT store to y).
// ---------------------------------------------------------------------------
__global__ __launch_bounds__(256) void final_fused(
    const float* __restrict__ hc,       // [B][C][H][W]
    const float* __restrict__ attnb,    // [32][1024]
    const float* __restrict__ Wout,     // [1024][1024]
    const float* __restrict__ bias,     // [1024]
    float* __restrict__ y)
{
    const int wave = threadIdx.x >> 6;
    const int lane = threadIdx.x & 63;
    const int wid = blockIdx.x * 4 + wave;    // 0..8191
    const int nwaves = gridDim.x * 4;
    const int nrows = BB * CC;

    for (int r0 = wid * 2; r0 < nrows; r0 += nwaves * 2) {
        const int r1 = r0 + 1;
        const int b0 = r0 >> 10, c0 = r0 & (CC - 1);
        const int b1 = r1 >> 10, c1 = r1 & (CC - 1);

        const v4f* a0 = (const v4f*)(attnb + (size_t)b0 * CC);
        const v4f* a1 = (const v4f*)(attnb + (size_t)b1 * CC);
        const v4f* w0 = (const v4f*)(Wout + (size_t)c0 * CC);
        const v4f* w1 = (const v4f*)(Wout + (size_t)c1 * CC);
        v4f acc0 = {0.f, 0.f, 0.f, 0.f};
        v4f acc1 = {0.f, 0.f, 0.f, 0.f};
#pragma unroll
        for (int j = 0; j < 4; ++j) {
            acc0 += a0[lane + 64 * j] * w0[lane + 64 * j];
            acc1 += a1[lane + 64 * j] * w1[lane + 64 * j];
        }
        float d0 = acc0.x + acc0.y + acc0.z + acc0.w;
        float d1 = acc1.x + acc1.y + acc1.z + acc1.w;
#pragma unroll
        for (int off = 32; off; off >>= 1) {
            d0 += __shfl_xor(d0, off);
            d1 += __shfl_xor(d1, off);
        }
        const float add0 = d0 + bias[c0];
        const float add1 = d1 + bias[c1];

        const v4f* s0 = (const v4f*)(hc + (size_t)r0 * HWSZ);
        const v4f* s1 = (const v4f*)(hc + (size_t)r1 * HWSZ);
        v4f* o0 = (v4f*)(y + (size_t)r0 * HWSZ);
        v4f* o1 = (v4f*)(y + (size_t)r1 * HWSZ);

        v4f u0 = s0[lane];
        v4f u1 = s1[lane];
        u0.x += add0; u0.y += add0; u0.z += add0; u0.w += add0;
        u1.x += add1; u1.y += add1; u1.z += add1; u1.w += add1;
        __builtin_nontemporal_store(u0, o0 + lane);
        __builtin_nontemporal_store(u1, o1 + lane);
        v4f u2 = s0[lane + 64];
        v4f u3 = s1[lane + 64];
        u2.x += add0; u2.y += add0; u2.z += add0; u2.w += add0;
        u3.x += add1; u3.y += add1; u3.z += add1; u3.w += add1;
        __builtin_nontemporal_store(u2, o0 + lane + 64);
        __builtin_nontemporal_store(u3, o1 + lane + 64);
        if (lane < 16) {
            v4f u4 = s0[lane + 128];
            v4f u5 = s1[lane + 128];
            u4.x += add0; u4.y += add0; u4.z += add0; u4.w += add0;
            u5.x += add1; u5.y += add1; u5.z += add1; u5.w += add1;
            __builtin_nontemporal_store(u4, o0 + lane + 128);
            __builtin_nontemporal_store(u5, o1 + lane + 128);
        }
    }
}

// ---------------------------------------------------------------------------
extern "C" void kernel_launch(void* const* d_in, const int* in_sizes, int n_in,
                              void* d_out, int out_size, void* d_ws, size_t ws_size,
                              hipStream_t stream) {
    const float* h_current = (const float*)d_in[0];  // [32,1024,18,32]
    const float* h_buffer  = (const float*)d_in[1];  // [8,32,1024,18,32]
    const float* W_qkv     = (const float*)d_in[2];  // [3072,1024]
    const float* W_out     = (const float*)d_in[3];  // [1024,1024]
    const float* b_out     = (const float*)d_in[4];  // [1024]
    const float* rel_emb   = (const float*)d_in[5];  // [17,8]

    float* ws = (float*)d_ws;
    float* ctx    = ws;                                   // 294912
    float* kvpart = ctx + 294912;                         // 4 * 589824
    float* qpart  = kvpart + (size_t)NS_KV * KV_MN;       // 8 * 32768
    float* attnb  = qpart + (size_t)NS_Q * Q_MN;          // 32768
    // total ~11.8 MB

    // K1: pooling (16 lanes/row, grid-stride; buffer NT-first, current last)
    pool_kernel<<<2048, 256, 0, stream>>>(h_buffer, h_current, ctx);

    // K2: Q + KV projections (640 blocks, all co-resident)
    qkv_gemm<<<NS_Q * 8 + NS_KV * 144, 256, 0, stream>>>(ctx, W_qkv, qpart, kvpart);

    // K3: attention (256 single-wave blocks)
    attn_kernel<<<BB * NH, 64, 0, stream>>>(kvpart, qpart, rel_emb, attnb);

    // K4: fused out-projection + broadcast residual add (2 rows/wave-iter)
    final_fused<<<2048, 256, 0, stream>>>(h_current, attnb, W_out, b_out, (float*)d_out);
}

// Round 7
// 154.611 us; speedup vs baseline: 1.0878x; 1.0878x over previous
//
#include <hip/hip_runtime.h>
#include <hip/hip_bf16.h>

// Shapes (fixed by the reference)
#define BB 32          // batch
#define CC 1024        // channels
#define HWSZ 576       // H*W
#define KCTX 8         // CONTEXT_LEN
#define TT 9           // K+1
#define NH 8
#define HD 128

#define NS 4           // split-K for both projections (k-slice 256)
#define KV_MN (288 * 2048)
#define Q_MN  (32 * 1024)

typedef float v4f __attribute__((ext_vector_type(4)));
typedef __attribute__((ext_vector_type(8))) short  bf16x8;
typedef __attribute__((ext_vector_type(8))) ushort u16x8;
typedef __attribute__((ext_vector_type(4))) float  f32x4;

__device__ __forceinline__ ushort f2bf(float f) {
    uint u = __builtin_bit_cast(uint, f);
    return (ushort)((u + 0x7FFFu + ((u >> 16) & 1u)) >> 16);   // RNE
}

// ---------------------------------------------------------------------------
// K1: spatial mean pooling -> context [B][T][C] in BF16, plus W_qkv fp32->bf16
// conversion tail. 16 lanes per row, 4 rows per wave. Buffer rows (memory
// order, NT loads) first; h_current rows last cached (L3-resident for K4).
// ---------------------------------------------------------------------------
__global__ __launch_bounds__(256) void pool_kernel(
    const float* __restrict__ hbuf,   // [K][B][C][H][W]
    const float* __restrict__ hcur,   // [B][C][H][W]
    const float* __restrict__ Wqkv,   // [3072][1024] fp32
    ushort* __restrict__ ctxb,        // [B][T][C] bf16
    ushort* __restrict__ Wb)          // [3072][1024] bf16
{
    const int wave = threadIdx.x >> 6;
    const int lane = threadIdx.x & 63;
    const int sub  = lane >> 4;        // row-within-wave 0..3
    const int l16  = lane & 15;
    const int stride = gridDim.x * 16; // rows per full sweep
    const int nrows = BB * TT * CC;    // 294912

    for (int r0 = (blockIdx.x * 4 + wave) * 4; r0 < nrows; r0 += stride) {
        const int r = r0 + sub;
        v4f acc = {0.f, 0.f, 0.f, 0.f};
        int cidx;
        if (r < KCTX * BB * CC) {                 // buffer rows, memory order
            const v4f* s4 = (const v4f*)(hbuf + (size_t)r * HWSZ);
            const int t = r >> 15;
            const int b = (r >> 10) & 31;
            cidx = (b * TT + t) * CC + (r & (CC - 1));
#pragma unroll
            for (int j = 0; j < 9; ++j)
                acc += __builtin_nontemporal_load(s4 + l16 + 16 * j);
        } else {                                  // current rows, last, cached
            const int rc = r - KCTX * BB * CC;
            const v4f* s4 = (const v4f*)(hcur + (size_t)rc * HWSZ);
            cidx = ((rc >> 10) * TT + KCTX) * CC + (rc & (CC - 1));
#pragma unroll
            for (int j = 0; j < 9; ++j)
                acc += s4[l16 + 16 * j];
        }
        float sum = acc.x + acc.y + acc.z + acc.w;
        sum += __shfl_xor(sum, 1);
        sum += __shfl_xor(sum, 2);
        sum += __shfl_xor(sum, 4);
        sum += __shfl_xor(sum, 8);
        if (l16 == 0) ctxb[cidx] = f2bf(sum * (1.0f / 576.0f));
    }

    // W_qkv fp32 -> bf16 (3072*1024/8 = 393216 chunks of 8)
    const int nchunk = 3072 * 1024 / 8;
    for (int idx = blockIdx.x * 256 + threadIdx.x; idx < nchunk;
         idx += gridDim.x * 256) {
        const float* src = Wqkv + (size_t)idx * 8;
        v4f a = *(const v4f*)src;
        v4f b = *(const v4f*)(src + 4);
        u16x8 o;
        o[0] = f2bf(a.x); o[1] = f2bf(a.y); o[2] = f2bf(a.z); o[3] = f2bf(a.w);
        o[4] = f2bf(b.x); o[5] = f2bf(b.y); o[6] = f2bf(b.z); o[7] = f2bf(b.w);
        *(u16x8*)(Wb + (size_t)idx * 8) = o;
    }
}

// ---------------------------------------------------------------------------
// K2: Q + KV projections via bf16 MFMA (no LDS; A/B straight from L2).
// 1216 wave-tiles: [0,1152) KV (18 mt x 16 nt x 4 splits, tile 16x128),
// [1152,1216) Q (2 mt x 8 nt x 4 splits). Partials fp32.
// Fragment mapping (m89-verified): A lane: row=lane&15, k=(lane>>4)*8+j;
// B lane: col(n)=lane&15, same k (reads W[n][k..k+7] contiguous);
// D: row=(lane>>4)*4+i, col=lane&15.
// ---------------------------------------------------------------------------
__global__ __launch_bounds__(256) void qkv_mfma(
    const ushort* __restrict__ ctxb, const ushort* __restrict__ Wb,
    float* __restrict__ qpart, float* __restrict__ kvpart)
{
    const int wave = threadIdx.x >> 6;
    const int lane = threadIdx.x & 63;
    const int t = blockIdx.x * 4 + wave;   // 0..1215
    const int l15 = lane & 15;
    const int kg  = lane >> 4;             // 0..3

    const ushort* abase;
    const ushort* bbase;
    float* out;
    int ldy, outrow0, outcol0;

    if (t < 1152) {                        // KV tiles
        const int s  = t & 3;
        const int tt = t >> 2;             // 0..287
        const int mt = tt / 16, nt = tt % 16;
        const int k0 = s * 256;
        abase = ctxb + (size_t)(mt * 16 + l15) * 1024 + k0 + kg * 8;
        bbase = Wb + (size_t)(1024 + nt * 128 + l15) * 1024 + k0 + kg * 8;
        out = kvpart + (size_t)s * KV_MN;
        ldy = 2048;
        outrow0 = mt * 16 + kg * 4;
        outcol0 = nt * 128 + l15;
    } else {                               // Q tiles
        const int r  = t - 1152;           // 0..63
        const int s  = r & 3;
        const int tt = r >> 2;             // 0..15
        const int mt = tt >> 3, nt = tt & 7;
        const int k0 = s * 256;
        abase = ctxb + (size_t)((mt * 16 + l15) * 9 + 8) * 1024 + k0 + kg * 8;
        bbase = Wb + (size_t)(nt * 128 + l15) * 1024 + k0 + kg * 8;
        out = qpart + (size_t)s * Q_MN;
        ldy = 1024;
        outrow0 = mt * 16 + kg * 4;
        outcol0 = nt * 128 + l15;
    }

    f32x4 acc0 = {0,0,0,0}, acc1 = {0,0,0,0}, acc2 = {0,0,0,0}, acc3 = {0,0,0,0};
    f32x4 acc4 = {0,0,0,0}, acc5 = {0,0,0,0}, acc6 = {0,0,0,0}, acc7 = {0,0,0,0};

#pragma unroll
    for (int kk = 0; kk < 8; ++kk) {       // 8 k-steps of 32 (k-slice 256)
        bf16x8 a = *(const bf16x8*)(abase + kk * 32);
        const ushort* bp = bbase + kk * 32;
        bf16x8 b0 = *(const bf16x8*)(bp + 0 * 16 * 1024);
        bf16x8 b1 = *(const bf16x8*)(bp + 1 * 16 * 1024);
        bf16x8 b2 = *(const bf16x8*)(bp + 2 * 16 * 1024);
        bf16x8 b3 = *(const bf16x8*)(bp + 3 * 16 * 1024);
        bf16x8 b4 = *(const bf16x8*)(bp + 4 * 16 * 1024);
        bf16x8 b5 = *(const bf16x8*)(bp + 5 * 16 * 1024);
        bf16x8 b6 = *(const bf16x8*)(bp + 6 * 16 * 1024);
        bf16x8 b7 = *(const bf16x8*)(bp + 7 * 16 * 1024);
        acc0 = __builtin_amdgcn_mfma_f32_16x16x32_bf16(a, b0, acc0, 0, 0, 0);
        acc1 = __builtin_amdgcn_mfma_f32_16x16x32_bf16(a, b1, acc1, 0, 0, 0);
        acc2 = __builtin_amdgcn_mfma_f32_16x16x32_bf16(a, b2, acc2, 0, 0, 0);
        acc3 = __builtin_amdgcn_mfma_f32_16x16x32_bf16(a, b3, acc3, 0, 0, 0);
        acc4 = __builtin_amdgcn_mfma_f32_16x16x32_bf16(a, b4, acc4, 0, 0, 0);
        acc5 = __builtin_amdgcn_mfma_f32_16x16x32_bf16(a, b5, acc5, 0, 0, 0);
        acc6 = __builtin_amdgcn_mfma_f32_16x16x32_bf16(a, b6, acc6, 0, 0, 0);
        acc7 = __builtin_amdgcn_mfma_f32_16x16x32_bf16(a, b7, acc7, 0, 0, 0);
    }

    float* yb = out + (size_t)outrow0 * ldy + outcol0;
#pragma unroll
    for (int i = 0; i < 4; ++i) {
        float* yr = yb + (size_t)i * ldy;
        yr[0 * 16] = acc0[i]; yr[1 * 16] = acc1[i];
        yr[2 * 16] = acc2[i]; yr[3 * 16] = acc3[i];
        yr[4 * 16] = acc4[i]; yr[5 * 16] = acc5[i];
        yr[6 * 16] = acc6[i]; yr[7 * 16] = acc7[i];
    }
}

// ---------------------------------------------------------------------------
// K3: attention, last query only. One wave per block, 256 blocks.
// Sums split-K partials of q and kv inline (L2-hot).
// ---------------------------------------------------------------------------
__global__ __launch_bounds__(64) void attn_kernel(
    const float* __restrict__ kvpart,   // NS slabs of [288][2048]
    const float* __restrict__ qpart,    // NS slabs of [32][1024]
    const float* __restrict__ rel_emb,  // [17][8]
    float* __restrict__ attn_out)       // [B][C]
{
    const int lane = threadIdx.x;
    const int pair = blockIdx.x;              // 0..255
    const int b = pair >> 3;
    const int h = pair & 7;
    const float scale = 0.08838834764831845f; // 1/sqrt(128)

    const int qoff = b * CC + h * HD;
    float q1 = 0.f, q2 = 0.f;
#pragma unroll
    for (int s = 0; s < NS; ++s) {
        q1 += qpart[(size_t)s * Q_MN + qoff + lane];
        q2 += qpart[(size_t)s * Q_MN + qoff + lane + 64];
    }
    q1 *= scale; q2 *= scale;

    float sc[TT];
#pragma unroll
    for (int j = 0; j < TT; ++j) {
        const size_t base = (size_t)(b * TT + j) * 2048 + h * HD;
        float k1 = 0.f, k2 = 0.f;
#pragma unroll
        for (int s = 0; s < NS; ++s) {
            k1 += kvpart[(size_t)s * KV_MN + base + lane];
            k2 += kvpart[(size_t)s * KV_MN + base + lane + 64];
        }
        float p = q1 * k1 + q2 * k2;
#pragma unroll
        for (int off = 32; off; off >>= 1) p += __shfl_xor(p, off);
        sc[j] = p + rel_emb[(2 * KCTX - j) * NH + h];
    }
    float m = sc[0];
#pragma unroll
    for (int j = 1; j < TT; ++j) m = fmaxf(m, sc[j]);
    float sum = 0.f;
#pragma unroll
    for (int j = 0; j < TT; ++j) { sc[j] = expf(sc[j] - m); sum += sc[j]; }
    const float inv = 1.0f / sum;

    float a1 = 0.f, a2 = 0.f;
#pragma unroll
    for (int j = 0; j < TT; ++j) {
        const size_t base = (size_t)(b * TT + j) * 2048 + 1024 + h * HD;
        float v1 = 0.f, v2 = 0.f;
#pragma unroll
        for (int s = 0; s < NS; ++s) {
            v1 += kvpart[(size_t)s * KV_MN + base + lane];
            v2 += kvpart[(size_t)s * KV_MN + base + lane + 64];
        }
        a1 += sc[j] * v1;
        a2 += sc[j] * v2;
    }
    attn_out[qoff + lane] = a1 * inv;
    attn_out[qoff + lane + 64] = a2 * inv;
}

// ---------------------------------------------------------------------------
// K4: fused out-projection + broadcast residual add (R5-proven single-row).
// One wave per output row: dot(attnb[b,:], Wout[c,:]) from L2, + bias,
// broadcast-add over 576 spatial floats (L3-hot h_current), NT store.
// ---------------------------------------------------------------------------
__global__ __launch_bounds__(256) void final_fused(
    const float* __restrict__ hc,       // [B][C][H][W]
    const float* __restrict__ attnb,    // [32][1024]
    const float* __restrict__ Wout,     // [1024][1024]
    const float* __restrict__ bias,     // [1024]
    float* __restrict__ y)
{
    const int wave = threadIdx.x >> 6;
    const int lane = threadIdx.x & 63;
    const int stride = gridDim.x * 4;
    const int nrows = BB * CC;

    for (int r = blockIdx.x * 4 + wave; r < nrows; r += stride) {
        const int b = r >> 10;
        const int c = r & (CC - 1);

        const v4f* ar = (const v4f*)(attnb + (size_t)b * CC);
        const v4f* wr = (const v4f*)(Wout + (size_t)c * CC);
        v4f acc = {0.f, 0.f, 0.f, 0.f};
#pragma unroll
        for (int j = 0; j < 4; ++j) {
            v4f a = ar[lane + 64 * j];
            v4f w = wr[lane + 64 * j];
            acc += a * w;
        }
        float dot = acc.x + acc.y + acc.z + acc.w;
#pragma unroll
        for (int off = 32; off; off >>= 1) dot += __shfl_xor(dot, off);
        const float add = dot + bias[c];

        const v4f* s4 = (const v4f*)(hc + (size_t)r * HWSZ);
        v4f* d4 = (v4f*)(y + (size_t)r * HWSZ);
        v4f v0 = s4[lane];
        v0.x += add; v0.y += add; v0.z += add; v0.w += add;
        __builtin_nontemporal_store(v0, d4 + lane);
        v4f v1 = s4[lane + 64];
        v1.x += add; v1.y += add; v1.z += add; v1.w += add;
        __builtin_nontemporal_store(v1, d4 + lane + 64);
        if (lane < 16) {
            v4f v2 = s4[lane + 128];
            v2.x += add; v2.y += add; v2.z += add; v2.w += add;
            __builtin_nontemporal_store(v2, d4 + lane + 128);
        }
    }
}

// ---------------------------------------------------------------------------
extern "C" void kernel_launch(void* const* d_in, const int* in_sizes, int n_in,
                              void* d_out, int out_size, void* d_ws, size_t ws_size,
                              hipStream_t stream) {
    const float* h_current = (const float*)d_in[0];  // [32,1024,18,32]
    const float* h_buffer  = (const float*)d_in[1];  // [8,32,1024,18,32]
    const float* W_qkv     = (const float*)d_in[2];  // [3072,1024]
    const float* W_out     = (const float*)d_in[3];  // [1024,1024]
    const float* b_out     = (const float*)d_in[4];  // [1024]
    const float* rel_emb   = (const float*)d_in[5];  // [17,8]

    ushort* ctxb = (ushort*)d_ws;                    // 294912 bf16
    ushort* Wb   = ctxb + 294912;                    // 3145728 bf16
    float* kvpart = (float*)(Wb + 3145728);          // 4 * 589824 fp32
    float* qpart  = kvpart + (size_t)NS * KV_MN;     // 4 * 32768
    float* attnb  = qpart + (size_t)NS * Q_MN;       // 32768
    // total ~16.7 MB

    // K1: pooling -> bf16 ctx, + W_qkv bf16 conversion tail
    pool_kernel<<<2048, 256, 0, stream>>>(h_buffer, h_current, W_qkv, ctxb, Wb);

    // K2: Q + KV projections via MFMA (304 blocks = 1216 wave-tiles)
    qkv_mfma<<<304, 256, 0, stream>>>(ctxb, Wb, qpart, kvpart);

    // K3: attention (256 single-wave blocks)
    attn_kernel<<<BB * NH, 64, 0, stream>>>(kvpart, qpart, rel_emb, attnb);

    // K4: fused out-projection + broadcast residual add
    final_fused<<<2048, 256, 0, stream>>>(h_current, attnb, W_out, b_out, (float*)d_out);
}